// Round 9
// baseline (188.405 us; speedup 1.0000x reference)
//
#include <hip/hip_runtime.h>

#define IMG_H 512
#define IMG_W 512
#define HW (IMG_H * IMG_W)
#define NB 32
#define STRIPS 32           // strips per image; strip = 16 rows
#define SROWS 16

// Workspace layout (no zero-init required — every slot is fully overwritten):
//   hist_part: 32 images x 32 strips x 256 bins (uint)   @ 0        (1 MB)
//   acc_part:  32 images x 32 strips x 5 (double)        @ 1 MB     (40 KB)
//   acc k-order: 0=lap_sum 1=lap_sq 2=depth_n 3=depth_sum 4=depth_sq
#define ACC_OFF (NB * STRIPS * 256 * 4)

// One streaming pass, k1-shaped loads (flat, independent, coalesced 1KB/wave),
// stencil served from an LDS gray tile (16 main rows + 2 halo rows).
// Per-block partial outputs -> no global atomics, no memset dispatch.
__global__ __launch_bounds__(256, 4) void stream_kernel(
    const float* __restrict__ rgb, const float* __restrict__ depth,
    unsigned int* __restrict__ hist_part, double* __restrict__ acc_part)
{
    __shared__ float gray[SROWS + 2][IMG_W];   // 36864 B
    __shared__ unsigned int lh[2][256];
    __shared__ double red[4][5];

    const int t = threadIdx.x;
    const int b = blockIdx.y;
    const int s = blockIdx.x;
    const int lane = t & 63;
    const int w = t >> 6;

    lh[0][t] = 0u;
    lh[1][t] = 0u;
    __syncthreads();

    const float* rp = rgb + (size_t)b * 3 * HW;
    const float4* dp = (const float4*)(depth + (size_t)b * HW) + s * 2048;

    // ---- halo rows (wave-uniform row selection; waves 0,1 top / 2,3 bottom) ----
    {
        const int hr = (w < 2) ? (SROWS * s - 1) : (SROWS * s + SROWS);
        const int lr = (w < 2) ? 0 : (SROWS + 1);
        const int c4 = (w < 2) ? t : (t - 128);          // 0..127
        float4 gv = {0.f, 0.f, 0.f, 0.f};
        if ((unsigned)hr < IMG_H) {
            const size_t o = (size_t)hr * IMG_W + 4 * c4;
            const float4 r4 = *(const float4*)(rp + o);
            const float4 g4 = *(const float4*)(rp + HW + o);
            const float4 b4 = *(const float4*)(rp + 2 * HW + o);
            gv.x = 0.299f * r4.x + 0.587f * g4.x + 0.114f * b4.x;
            gv.y = 0.299f * r4.y + 0.587f * g4.y + 0.114f * b4.y;
            gv.z = 0.299f * r4.z + 0.587f * g4.z + 0.114f * b4.z;
            gv.w = 0.299f * r4.w + 0.587f * g4.w + 0.114f * b4.w;
        }
        *(float4*)&gray[lr][4 * c4] = gv;
    }

    // ---- main streaming loop: flat independent loads (k1 shape) ----
    float dnf = 0.f, dsf = 0.f, dqf = 0.f;
    #pragma unroll
    for (int i = 0; i < 8; ++i) {
        const int p = i * 256 + t;            // float4 index in strip
        const int r = p >> 7;                 // main row 0..15
        const int c4 = p & 127;
        const size_t o = (size_t)(SROWS * s + r) * IMG_W + 4 * c4;
        const float4 r4 = *(const float4*)(rp + o);
        const float4 g4 = *(const float4*)(rp + HW + o);
        const float4 b4 = *(const float4*)(rp + 2 * HW + o);
        const float4 d4 = dp[p];
        float4 gv;
        gv.x = 0.299f * r4.x + 0.587f * g4.x + 0.114f * b4.x;
        gv.y = 0.299f * r4.y + 0.587f * g4.y + 0.114f * b4.y;
        gv.z = 0.299f * r4.z + 0.587f * g4.z + 0.114f * b4.z;
        gv.w = 0.299f * r4.w + 0.587f * g4.w + 0.114f * b4.w;
        *(float4*)&gray[r + 1][4 * c4] = gv;
        atomicAdd(&lh[w & 1][(int)fminf(fmaxf(gv.x * 255.f, 0.f), 255.f)], 1u);
        atomicAdd(&lh[w & 1][(int)fminf(fmaxf(gv.y * 255.f, 0.f), 255.f)], 1u);
        atomicAdd(&lh[w & 1][(int)fminf(fmaxf(gv.z * 255.f, 0.f), 255.f)], 1u);
        atomicAdd(&lh[w & 1][(int)fminf(fmaxf(gv.w * 255.f, 0.f), 255.f)], 1u);
        if (d4.x > 0.f) { dnf += 1.f; dsf += d4.x; dqf += d4.x * d4.x; }
        if (d4.y > 0.f) { dnf += 1.f; dsf += d4.y; dqf += d4.y * d4.y; }
        if (d4.z > 0.f) { dnf += 1.f; dsf += d4.z; dqf += d4.z * d4.z; }
        if (d4.w > 0.f) { dnf += 1.f; dsf += d4.w; dqf += d4.w * d4.w; }
    }

    __syncthreads();

    // ---- stencil from LDS ----
    float s1 = 0.f, s2 = 0.f;
    #pragma unroll
    for (int i = 0; i < 8; ++i) {
        const int p = i * 256 + t;
        const int r = p >> 7;
        const int c = 4 * (p & 127);
        const float4 up = *(const float4*)&gray[r][c];
        const float4 ce = *(const float4*)&gray[r + 1][c];
        const float4 dn = *(const float4*)&gray[r + 2][c];
        const float lf = (c > 0) ? gray[r + 1][c - 1] : 0.f;
        const float rt = (c < IMG_W - 4) ? gray[r + 1][c + 4] : 0.f;
        float4 lap;
        lap.x = up.x + dn.x + lf   + ce.y - 4.f * ce.x;
        lap.y = up.y + dn.y + ce.x + ce.z - 4.f * ce.y;
        lap.z = up.z + dn.z + ce.y + ce.w - 4.f * ce.z;
        lap.w = up.w + dn.w + ce.z + rt   - 4.f * ce.w;
        s1 += lap.x + lap.y + lap.z + lap.w;
        s2 += lap.x * lap.x + lap.y * lap.y + lap.z * lap.z + lap.w * lap.w;
    }

    // ---- block reduction of the 5 scalars ----
    double z0 = (double)s1, z1 = (double)s2, z2 = (double)dnf, z3 = (double)dsf, z4 = (double)dqf;
    for (int off = 32; off > 0; off >>= 1) {
        z0 += __shfl_down(z0, off, 64);
        z1 += __shfl_down(z1, off, 64);
        z2 += __shfl_down(z2, off, 64);
        z3 += __shfl_down(z3, off, 64);
        z4 += __shfl_down(z4, off, 64);
    }
    if (lane == 0) {
        red[w][0] = z0; red[w][1] = z1; red[w][2] = z2; red[w][3] = z3; red[w][4] = z4;
    }
    __syncthreads();   // covers lh atomics and red[] writes

    hist_part[(b * STRIPS + s) * 256 + t] = lh[0][t] + lh[1][t];
    if (t < 5) {
        acc_part[(b * STRIPS + s) * 5 + t] =
            red[0][t] + red[1][t] + red[2][t] + red[3][t];
    }
}

// One block per image: reduce partials, entropy, final formulas.
__global__ __launch_bounds__(256) void final_kernel(
    const unsigned int* __restrict__ hist_part,
    const double* __restrict__ acc_part,
    float* __restrict__ out)
{
    __shared__ double epart[4];
    __shared__ double asum[5];

    const int t = threadIdx.x;
    const int b = blockIdx.x;
    const int lane = t & 63;
    const int w = t >> 6;

    // histogram bin t summed over 32 strips (coalesced per iteration)
    const unsigned int* hp = hist_part + b * STRIPS * 256;
    unsigned int tot = 0;
    #pragma unroll
    for (int st = 0; st < STRIPS; ++st) tot += hp[st * 256 + t];
    const float p = (float)tot * (1.0f / (float)HW);
    double ed = (double)(p * log2f(p + 1e-4f));
    for (int off = 32; off > 0; off >>= 1) ed += __shfl_down(ed, off, 64);
    if (lane == 0) epart[w] = ed;

    // acc partials: wave 0, lane l holds strip l&31 (lanes >=32 contribute 0)
    if (w == 0) {
        double a[5];
        #pragma unroll
        for (int k = 0; k < 5; ++k)
            a[k] = (lane < STRIPS) ? acc_part[(b * STRIPS + lane) * 5 + k] : 0.0;
        for (int off = 32; off > 0; off >>= 1) {
            #pragma unroll
            for (int k = 0; k < 5; ++k) a[k] += __shfl_down(a[k], off, 64);
        }
        if (lane == 0) {
            #pragma unroll
            for (int k = 0; k < 5; ++k) asum[k] = a[k];
        }
    }
    __syncthreads();

    if (t == 0) {
        const double entropy = -(epart[0] + epart[1] + epart[2] + epart[3]);
        const double N = (double)HW;

        const double ls = asum[0], lq = asum[1];
        const double lvar = (lq - ls * ls / N) / (N - 1.0);
        const double clarity = lvar / (1000.0 + 1e-4);
        const double uniformity = 1.0 / (entropy + 1e-4);
        const double rgb_conf = 0.5 * (clarity + uniformity);

        const double n = asum[2], sdep = asum[3], q = asum[4];
        const double mean = sdep / fmax(n, 1.0);
        const double sq = q - 2.0 * mean * sdep + mean * mean * n;
        const double var = sq / fmax(n - 1.0, 1.0);
        const double stdd = sqrt(fmax(var, 0.0));
        const double noise = (n > 0.0) ? stdd : 1.0;
        const double density = n / N;
        const double depth_conf = 0.5 * (density / (10000.0 + 1e-4) + 1.0 / (noise + 1e-4));

        const double denom = rgb_conf + depth_conf + 1e-4;
        out[b]      = (float)(rgb_conf / denom);
        out[NB + b] = (float)(depth_conf / denom);
    }
}

extern "C" void kernel_launch(void* const* d_in, const int* in_sizes, int n_in,
                              void* d_out, int out_size, void* d_ws, size_t ws_size,
                              hipStream_t stream) {
    const float* rgb   = (const float*)d_in[0];
    const float* depth = (const float*)d_in[1];
    float* out = (float*)d_out;

    unsigned int* hist_part = (unsigned int*)d_ws;
    double* acc_part = (double*)((char*)d_ws + ACC_OFF);

    stream_kernel<<<dim3(STRIPS, NB), 256, 0, stream>>>(rgb, depth, hist_part, acc_part);
    final_kernel<<<NB, 256, 0, stream>>>(hist_part, acc_part, out);
}